// Round 10
// baseline (173.654 us; speedup 1.0000x reference)
//
#include <hip/hip_runtime.h>
#include <hip/hip_bf16.h>
#include <stdint.h>

// Problem sizes (fixed by reference)
#define BT     8
#define T_SEQ  4096
#define K_F    512
#define N_H    1024
#define M_TOT  (BT * T_SEQ)   // 32768
#define NLAYER 4
#define LC     32             // chunk length for parallel scan
#define NC     (T_SEQ / LC)   // 128 chunks

typedef short  bf16x8 __attribute__((ext_vector_type(8)));
typedef float  f32x4  __attribute__((ext_vector_type(4)));
typedef ushort u16x8  __attribute__((ext_vector_type(8)));
typedef ushort u16x4  __attribute__((ext_vector_type(4)));

// f32 -> bf16 (round-to-nearest-even)
__device__ __forceinline__ ushort f2bf(float f) {
  uint32_t u = __builtin_bit_cast(uint32_t, f);
  u += 0x7fffu + ((u >> 16) & 1u);
  return (ushort)(u >> 16);
}
__device__ __forceinline__ float bf2f(ushort u) {
  uint32_t x = (uint32_t)u << 16;
  return __builtin_bit_cast(float, x);
}

// async global->LDS, 16B per lane (global_load_lds_dwordx4).
__device__ __forceinline__ void gload16(const void* g, void* l) {
  __builtin_amdgcn_global_load_lds(
      (const __attribute__((address_space(1))) uint32_t*)g,
      (__attribute__((address_space(3))) uint32_t*)l, 16, 0, 0);
}

// ---------------- prep: x f32->bf16 (8192 blocks) | W transpose (512 blocks) --
#define CVT_BLOCKS ((M_TOT * K_F) / (256 * 8))   // 8192

__global__ __launch_bounds__(256) void prep_kernel(const float* __restrict__ x,
                                                   ushort* __restrict__ xb,
                                                   const float* __restrict__ W,
                                                   ushort* __restrict__ Wt) {
  __shared__ float tile[32][33];
  const int bid = blockIdx.x;
  if (bid < CVT_BLOCKS) {
    const int i = bid * 256 + threadIdx.x;
    const float4* xv = (const float4*)x;
    float4 v0 = xv[2 * i + 0];
    float4 v1 = xv[2 * i + 1];
    u16x8 o;
    o[0] = f2bf(v0.x); o[1] = f2bf(v0.y); o[2] = f2bf(v0.z); o[3] = f2bf(v0.w);
    o[4] = f2bf(v1.x); o[5] = f2bf(v1.y); o[6] = f2bf(v1.z); o[7] = f2bf(v1.w);
    *((u16x8*)xb + i) = o;
  } else {
    const int idx = bid - CVT_BLOCKS;       // 0..511
    const int k0 = (idx & 15) * 32;         // 16 K-tiles
    const int n0 = (idx >> 4) * 32;         // 32 N-tiles
    const int lx = threadIdx.x & 31;
    const int ly = threadIdx.x >> 5;
#pragma unroll
    for (int j = 0; j < 32; j += 8)
      tile[ly + j][lx] = W[(size_t)(k0 + ly + j) * N_H + n0 + lx];
    __syncthreads();
#pragma unroll
    for (int j = 0; j < 32; j += 8)
      Wt[(size_t)(n0 + ly + j) * K_F + k0 + lx] = f2bf(tile[lx][ly + j]);
  }
}

// ---------------- GEMM + fused chunk-state -------------------------------
// Yb[M][N] = bf16(Xb[M][K] * Wt[N][K]^T + bias). R7's proven 2-barrier m97
// schedule, geometry widened: BM=256, BN=128, BK=64, 8 waves (4Mx2N, per-wave
// 64x64 = identical fragment shapes to R7), grid (128,8)=1024 blocks.
// vs R7: total LDS staging 512->384 MB, A re-staging halved, barrier pairs
// per output halved; per-wave inner loop unchanged (zero new layout risk).
// Epilogue: two 128x128 halves, each exactly R7's verified epilogue
// (LDS-staged coalesced Yb store + fused chunk-state, bit-identical math).
#define BM 256
#define BN 128
#define BKK 64

__global__ __launch_bounds__(512) void gemm_kernel(
    const ushort* __restrict__ Xb, const ushort* __restrict__ Wt,
    const float* __restrict__ bias, ushort* __restrict__ Yb,
    const float* __restrict__ As, const float* __restrict__ Bs,
    const float* __restrict__ Cs, const float* __restrict__ Ds,
    float* __restrict__ E) {
  __shared__ ushort lds[24576];          // 48 KiB: lsA 32K | lsB 16K
  ushort* lsA  = lds;                    // [256][64]
  ushort* lsB  = lds + 16384;            // [128][64]
  ushort* tile = lds;                    // epilogue: [128][128] bf16 (32 KiB)

  const int tid  = threadIdx.x;
  const int lane = tid & 63;
  const int wv   = tid >> 6;     // wave 0..7
  const int wr   = wv >> 1;      // 0..3 -> 64-row band
  const int wc   = wv & 1;       // 0..1 -> 64-col half
  const int m0   = blockIdx.x * BM;
  const int n0   = blockIdx.y * BN;

  const int srow = (lane >> 3);        // 0..7 within 1KB region
  const int scol = (lane & 7) * 8;     // k-elem offset
  const ushort* gA = Xb + (size_t)m0 * K_F + scol;
  const ushort* gB = Wt + (size_t)n0 * K_F + scol;

  f32x4 acc[4][4];
#pragma unroll
  for (int i = 0; i < 4; i++)
#pragma unroll
    for (int j = 0; j < 4; j++) acc[i][j] = (f32x4)0.0f;

  const int lr = lane & 15;
  const int kg = (lane >> 4) * 8;

  for (int kt = 0; kt < K_F; kt += BKK) {
    // A: 32 regions x 1KB (rows reg*8+srow); B: 16 regions x 1KB
#pragma unroll
    for (int i = 0; i < 4; i++) {
      const int reg = wv * 4 + i;          // 0..31
      gload16(gA + (size_t)(reg * 8 + srow) * K_F + kt, &lsA[reg * 512]);
    }
#pragma unroll
    for (int i = 0; i < 2; i++) {
      const int reg = wv * 2 + i;          // 0..15
      gload16(gB + (size_t)(reg * 8 + srow) * K_F + kt, &lsB[reg * 512]);
    }
    __syncthreads();   // drains vmcnt -> tiles ready

    bf16x8 af[4][2], bfr[4][2];
#pragma unroll
    for (int fm = 0; fm < 4; fm++)
#pragma unroll
      for (int kk = 0; kk < 2; kk++)
        af[fm][kk] = *(const bf16x8*)&lsA[(wr * 64 + fm * 16 + lr) * BKK + kk * 32 + kg];
#pragma unroll
    for (int fn = 0; fn < 4; fn++)
#pragma unroll
      for (int kk = 0; kk < 2; kk++)
        bfr[fn][kk] = *(const bf16x8*)&lsB[(wc * 64 + fn * 16 + lr) * BKK + kk * 32 + kg];

#pragma unroll
    for (int kk = 0; kk < 2; kk++)
#pragma unroll
      for (int fm = 0; fm < 4; fm++)
#pragma unroll
        for (int fn = 0; fn < 4; fn++)
          acc[fm][fn] = __builtin_amdgcn_mfma_f32_16x16x32_bf16(af[fm][kk], bfr[fn][kk],
                                                                acc[fm][fn], 0, 0, 0);
    __syncthreads();   // all ds_reads done before next stage overwrites
  }

  // ---- epilogue: two 128-row halves; each is R7's verified epilogue ----
  const int bidx = m0 >> 12;                 // batch
  const int c0   = (m0 & (T_SEQ - 1)) >> 5;  // first chunk of this block

  // coefficients: same h for both halves -> load once
  const int hl = tid & 127;
  const int h  = n0 + hl;
  float ca[4], cb[4], cc[4], cd[4];
#pragma unroll
  for (int l = 0; l < 4; l++) {
    ca[l] = 1.f / (1.f + __expf(-As[l * N_H + h]));
    cb[l] = Bs[l * N_H + h];
    cc[l] = Cs[l * N_H + h];
    cd[l] = Ds[l * N_H + h];
  }

#pragma unroll
  for (int half = 0; half < 2; half++) {
    // stage 1: waves with wr>>1 == half write their acc into tile (+bias)
    if ((wr >> 1) == half) {
#pragma unroll
      for (int fn = 0; fn < 4; fn++) {
        const int col = wc * 64 + fn * 16 + lr;
        const float bv = bias[n0 + col];
#pragma unroll
        for (int fm = 0; fm < 4; fm++) {
          const int row0 = (wr & 1) * 64 + fm * 16 + (lane >> 4) * 4;
#pragma unroll
          for (int i = 0; i < 4; i++)
            tile[(row0 + i) * BN + col] = f2bf(acc[fm][fn][i] + bv);
        }
      }
    }
    __syncthreads();

    // stage 2a: coalesced Yb store (256B rows), all 512 threads
    {
      const int erow = tid >> 4;            // 0..31
      const int ecol = (tid & 15) * 8;
#pragma unroll
      for (int p = 0; p < 4; p++) {
        const int row = p * 32 + erow;
        *(u16x8*)&Yb[(size_t)(m0 + half * 128 + row) * N_H + n0 + ecol] =
            *(const u16x8*)&tile[row * BN + ecol];
      }
    }
    // stage 2b: fused chunk-state (bit-identical to standalone pass)
    {
      const int ck = tid >> 7;              // chunk within half, 0..3
      float s[4] = {0.f, 0.f, 0.f, 0.f};
#pragma unroll 4
      for (int t = 0; t < LC; t++) {
        float xv = bf2f(tile[(ck * LC + t) * BN + hl]);
#pragma unroll
        for (int l = 0; l < 4; l++) {
          s[l] = fmaf(ca[l], s[l], cb[l] * xv);
          xv = fmaf(cc[l], s[l], cd[l]);
        }
      }
      f32x4 e;
      e[0] = s[0]; e[1] = s[1]; e[2] = s[2]; e[3] = s[3];
      ((f32x4*)E)[(size_t)(bidx * NC + c0 + half * 4 + ck) * N_H + h] = e;
    }
    __syncthreads();   // half's tile reads done before next half overwrites
  }
}

// ============ chunked parallel scan (passes B and C) ============
// Pass B: per-(b,h) serial combine over chunks with P=M^LC -> start states S.
__global__ __launch_bounds__(256) void chunk_scan_kernel(
    const float* __restrict__ A, const float* __restrict__ B,
    const float* __restrict__ C, const float* __restrict__ E,
    float* __restrict__ S) {
  const int idx = blockIdx.x * 256 + threadIdx.x;
  const int b = idx >> 10;
  const int h = idx & (N_H - 1);

  float a[4], bcoef[4], ccoef[4];
#pragma unroll
  for (int l = 0; l < 4; l++) {
    a[l] = 1.f / (1.f + __expf(-A[l * N_H + h]));
    bcoef[l] = B[l * N_H + h];
    ccoef[l] = C[l * N_H + h];
  }

  float m[4][4] = {};
  m[0][0] = a[0];
  m[1][0] = bcoef[1] * ccoef[0] * a[0];
  m[1][1] = a[1];
  m[2][0] = bcoef[2] * ccoef[1] * m[1][0];
  m[2][1] = bcoef[2] * ccoef[1] * a[1];
  m[2][2] = a[2];
  m[3][0] = bcoef[3] * ccoef[2] * m[2][0];
  m[3][1] = bcoef[3] * ccoef[2] * m[2][1];
  m[3][2] = bcoef[3] * ccoef[2] * a[2];
  m[3][3] = a[3];

  // P = M^LC, LC=32 -> 5 squarings
#pragma unroll
  for (int it = 0; it < 5; it++) {
    float t[4][4];
#pragma unroll
    for (int i = 0; i < 4; i++)
#pragma unroll
      for (int j = 0; j < 4; j++) {
        float acc = 0.f;
#pragma unroll
        for (int k = 0; k < 4; k++) acc = fmaf(m[i][k], m[k][j], acc);
        t[i][j] = acc;
      }
#pragma unroll
    for (int i = 0; i < 4; i++)
#pragma unroll
      for (int j = 0; j < 4; j++) m[i][j] = t[i][j];
  }

  float s[4] = {0.f, 0.f, 0.f, 0.f};
  const f32x4* Ep = (const f32x4*)E + (size_t)b * NC * N_H + h;
  f32x4* Sp = (f32x4*)S + (size_t)b * NC * N_H + h;
#pragma unroll 4
  for (int c = 0; c < NC; c++) {
    f32x4 sv;
    sv[0] = s[0]; sv[1] = s[1]; sv[2] = s[2]; sv[3] = s[3];
    Sp[(size_t)c * N_H] = sv;
    f32x4 e = Ep[(size_t)c * N_H];
    float ns[4];
#pragma unroll
    for (int i = 0; i < 4; i++) {
      float acc = e[i];
#pragma unroll
      for (int k = 0; k < 4; k++) acc = fmaf(m[i][k], s[k], acc);
      ns[i] = acc;
    }
#pragma unroll
    for (int i = 0; i < 4; i++) s[i] = ns[i];
  }
}

// Pass C: recurrence from exact start state; reads bf16 Y, writes f32 out
__global__ __launch_bounds__(256) void chunk_apply_kernel(
    const ushort* __restrict__ Yb, float* __restrict__ out,
    const float* __restrict__ A, const float* __restrict__ B,
    const float* __restrict__ C, const float* __restrict__ D,
    const float* __restrict__ S) {
  const int b  = blockIdx.x / NC;
  const int c  = blockIdx.x % NC;
  const int h4 = threadIdx.x << 2;

  float a[4][4], bb[4][4], cc[4][4], dd[4][4];
#pragma unroll
  for (int l = 0; l < 4; l++) {
    f32x4 av = *(const f32x4*)(A + l * N_H + h4);
    f32x4 bv = *(const f32x4*)(B + l * N_H + h4);
    f32x4 cv = *(const f32x4*)(C + l * N_H + h4);
    f32x4 dv = *(const f32x4*)(D + l * N_H + h4);
#pragma unroll
    for (int ch = 0; ch < 4; ch++) {
      a[l][ch]  = 1.f / (1.f + __expf(-av[ch]));
      bb[l][ch] = bv[ch]; cc[l][ch] = cv[ch]; dd[l][ch] = dv[ch];
    }
  }

  float s[4][4];
  const f32x4* sp = (const f32x4*)S + (size_t)(b * NC + c) * N_H + h4;
#pragma unroll
  for (int ch = 0; ch < 4; ch++) {
    f32x4 sv = sp[ch];
    s[0][ch] = sv[0]; s[1][ch] = sv[1]; s[2][ch] = sv[2]; s[3][ch] = sv[3];
  }

  const ushort* ybase = Yb + ((size_t)b * T_SEQ + (size_t)c * LC) * N_H + h4;
  f32x4* op = (f32x4*)(out + ((size_t)b * T_SEQ + (size_t)c * LC) * N_H) + (h4 >> 2);
#pragma unroll 4
  for (int t = 0; t < LC; t++) {
    u16x4 xv = *(const u16x4*)(ybase + (size_t)t * N_H);
    f32x4 ov;
#pragma unroll
    for (int ch = 0; ch < 4; ch++) {
      float x = bf2f(xv[ch]);
#pragma unroll
      for (int l = 0; l < 4; l++) {
        s[l][ch] = fmaf(a[l][ch], s[l][ch], bb[l][ch] * x);
        x = fmaf(cc[l][ch], s[l][ch], dd[l][ch]);
      }
      ov[ch] = x;
    }
    op[(size_t)t * (N_H / 4)] = ov;
  }
}

extern "C" void kernel_launch(void* const* d_in, const int* in_sizes, int n_in,
                              void* d_out, int out_size, void* d_ws, size_t ws_size,
                              hipStream_t stream) {
  const float* x    = (const float*)d_in[0];
  const float* W    = (const float*)d_in[1];
  const float* b_in = (const float*)d_in[2];
  const float* A    = (const float*)d_in[3];
  const float* B    = (const float*)d_in[4];
  const float* C    = (const float*)d_in[5];
  const float* bias = (const float*)d_in[6];
  float* out = (float*)d_out;

  // ws layout (512 MiB available):
  //   xb  [0,   32 MiB)  bf16 x
  //   Wt  [32,  33 MiB)  bf16 W^T
  //   Yb  [40, 104 MiB)  bf16 intermediate Y
  //   E   [112,128 MiB)  f32 chunk end states
  //   S   [128,144 MiB)  f32 chunk start states
  char* wsb = (char*)d_ws;
  ushort* xb = (ushort*)wsb;
  ushort* Wt = (ushort*)(wsb + (size_t)33 * 1024 * 1024 - (size_t)N_H * K_F * 2);
  ushort* Yb = (ushort*)(wsb + (size_t)40 * 1024 * 1024);
  float*  E  = (float*)(wsb + (size_t)112 * 1024 * 1024);
  float*  S  = E + (size_t)BT * NC * N_H * 4;

  prep_kernel<<<CVT_BLOCKS + 512, 256, 0, stream>>>(x, xb, W, Wt);
  gemm_kernel<<<dim3(M_TOT / BM, N_H / BN), 512, 0, stream>>>(xb, Wt, b_in, Yb,
                                                              A, B, C, bias, E);
  chunk_scan_kernel<<<(BT * N_H) / 256, 256, 0, stream>>>(A, B, C, E, S);
  chunk_apply_kernel<<<BT * NC, 256, 0, stream>>>(Yb, out, A, B, C, bias, S);
}

// Round 11
// 164.951 us; speedup vs baseline: 1.0528x; 1.0528x over previous
//
#include <hip/hip_runtime.h>
#include <hip/hip_bf16.h>
#include <stdint.h>

// Problem sizes (fixed by reference)
#define BT     8
#define T_SEQ  4096
#define K_F    512
#define N_H    1024
#define M_TOT  (BT * T_SEQ)   // 32768
#define NLAYER 4
#define LC     32             // chunk length for parallel scan
#define NC     (T_SEQ / LC)   // 128 chunks

typedef short  bf16x8 __attribute__((ext_vector_type(8)));
typedef float  f32x4  __attribute__((ext_vector_type(4)));
typedef ushort u16x8  __attribute__((ext_vector_type(8)));
typedef ushort u16x4  __attribute__((ext_vector_type(4)));

// f32 -> bf16 (round-to-nearest-even), scalar
__device__ __forceinline__ ushort f2bf(float f) {
  uint32_t u = __builtin_bit_cast(uint32_t, f);
  u += 0x7fffu + ((u >> 16) & 1u);
  return (ushort)(u >> 16);
}
__device__ __forceinline__ float bf2f(ushort u) {
  uint32_t x = (uint32_t)u << 16;
  return __builtin_bit_cast(float, x);
}
// packed f32x2 -> bf16x2 (RNE), single HW instruction (T12 recipe, m240)
__device__ __forceinline__ uint32_t cvtpk(float lo, float hi) {
  uint32_t r;
  asm("v_cvt_pk_bf16_f32 %0, %1, %2" : "=v"(r) : "v"(lo), "v"(hi));
  return r;
}

// async global->LDS, 16B per lane (global_load_lds_dwordx4).
__device__ __forceinline__ void gload16(const void* g, void* l) {
  __builtin_amdgcn_global_load_lds(
      (const __attribute__((address_space(1))) uint32_t*)g,
      (__attribute__((address_space(3))) uint32_t*)l, 16, 0, 0);
}

// ---------------- prep: W [K][N] f32 -> Wt [N][K] bf16 ----------------
__global__ __launch_bounds__(256) void prep_w_kernel(const float* __restrict__ W,
                                                     ushort* __restrict__ Wt) {
  __shared__ float tile[32][33];
  const int k0 = (blockIdx.x & 15) * 32;   // 16 K tiles
  const int n0 = (blockIdx.x >> 4) * 32;   // 32 N tiles
  const int lx = threadIdx.x & 31;
  const int ly = threadIdx.x >> 5;
#pragma unroll
  for (int j = 0; j < 32; j += 8)
    tile[ly + j][lx] = W[(size_t)(k0 + ly + j) * N_H + n0 + lx];
  __syncthreads();
#pragma unroll
  for (int j = 0; j < 32; j += 8)
    Wt[(size_t)(n0 + ly + j) * K_F + k0 + lx] = f2bf(tile[lx][ly + j]);
}

// ---------------- GEMM + fused chunk-state -------------------------------
// R7's proven geometry/schedule (128x128 tile, BK=64, 4 waves, 2048 blocks,
// ~4 blocks/CU) with the x f32->bf16 conversion folded into A-staging:
//   A: 8 coalesced float4 loads/thread from f32 x -> v_cvt_pk_bf16_f32 ->
//      XOR-swizzled ds_write_b64 (write conflict-free; read idx^((lr&7)<<3),
//      2-way aliasing = free). Eliminates the xb pre-pass (96 MB).
//   B: unchanged R7 path (global_load_lds width=16, linear).
// Sync = R2-proven double barrier per K-iter:
//   { A global loads -> sync#1 (prev tile reads drained) ->
//     cvt + A ds_write + B gload issue -> sync#2 (lgkm+vmcnt drained) ->
//     ds_read frags + 32 MFMA }    (stage never overlaps live reads; R8 lesson)
// Epilogue identical to R7: LDS-staged coalesced Yb store + fused chunk-state.
#define BM 128
#define BN 128
#define BKK 64

__global__ __launch_bounds__(512) void dummy_unused();  // (keep symbol table tidy)

__global__ __launch_bounds__(256) void gemm_kernel(
    const float* __restrict__ x, const ushort* __restrict__ Wt,
    const float* __restrict__ bias, ushort* __restrict__ Yb,
    const float* __restrict__ As, const float* __restrict__ Bs,
    const float* __restrict__ Cs, const float* __restrict__ Ds,
    float* __restrict__ E) {
  __shared__ ushort lds[BM * BKK * 2];   // 32 KiB: lsA [128][64] | lsB [128][64]
  ushort* lsA = lds;
  ushort* lsB = lds + BM * BKK;
  ushort* tile = lds;                    // epilogue: [128][128] bf16

  const int tid  = threadIdx.x;
  const int lane = tid & 63;
  const int wv   = tid >> 6;     // wave 0..3
  const int wr   = wv >> 1;      // wave row (0..1) -> 64 rows
  const int wc   = wv & 1;       // wave col (0..1) -> 64 cols
  const int m0   = blockIdx.x * BM;
  const int n0   = blockIdx.y * BN;

  const int lr = lane & 15;
  const int kg = (lane >> 4) * 8;
  const int aswz = (lr & 7) << 3;        // A-read swizzle: (row&7)*8 elems

  // A staging geometry: thread covers (row = j*16 + tid>>4, col4 = tid&15)
  const int arow_lo = tid >> 4;          // 0..15
  const int acol4   = tid & 15;          // f32x4 column within 64-f32 tile
  const int wswz    = (arow_lo & 7) << 3;      // write swizzle (row&7)*8 elems
  const int adst    = (acol4 * 4) ^ wswz;      // swizzled elem offset in row
  const float4* xs  = (const float4*)(x + (size_t)m0 * K_F);

  // B staging (R7 exact): 16 regions x 1KB
  const int srow = (lane >> 3);
  const int scol = (lane & 7) * 8;
  const ushort* gB = Wt + (size_t)n0 * K_F + scol;

  f32x4 acc[4][4];
#pragma unroll
  for (int i = 0; i < 4; i++)
#pragma unroll
    for (int j = 0; j < 4; j++) acc[i][j] = (f32x4)0.0f;

  for (int kt8 = 0; kt8 < 8; kt8++) {
    // ---- A global loads (f32x4), coalesced: 16-lane groups read full rows --
    float4 av[8];
#pragma unroll
    for (int j = 0; j < 8; j++)
      av[j] = xs[(size_t)(j * 16 + arow_lo) * (K_F / 4) + kt8 * 16 + acol4];

    __syncthreads();   // #1: all waves' previous-tile ds_reads drained

    // ---- A: cvt + swizzled ds_write_b64 ----
#pragma unroll
    for (int j = 0; j < 8; j++) {
      uint2 r;
      r.x = cvtpk(av[j].x, av[j].y);
      r.y = cvtpk(av[j].z, av[j].w);
      *(uint2*)&lsA[(j * 16 + arow_lo) * BKK + adst] = r;
    }
    // ---- B: async gload (dest free since sync#1) ----
#pragma unroll
    for (int i = 0; i < 4; i++) {
      const int reg = wv * 4 + i;          // 0..15
      gload16(gB + (size_t)(reg * 8 + srow) * K_F + kt8 * 64, &lsB[reg * 512]);
    }

    __syncthreads();   // #2: drains lgkm (A writes) + vmcnt (B gload)

    bf16x8 af[4][2], bfr[4][2];
#pragma unroll
    for (int fm = 0; fm < 4; fm++) {
      const int row = wr * 64 + fm * 16 + lr;
#pragma unroll
      for (int kk = 0; kk < 2; kk++)
        af[fm][kk] = *(const bf16x8*)&lsA[row * BKK + ((kk * 32 + kg) ^ aswz)];
    }
#pragma unroll
    for (int fn = 0; fn < 4; fn++)
#pragma unroll
      for (int kk = 0; kk < 2; kk++)
        bfr[fn][kk] = *(const bf16x8*)&lsB[(wc * 64 + fn * 16 + lr) * BKK + kk * 32 + kg];

#pragma unroll
    for (int kk = 0; kk < 2; kk++)
#pragma unroll
      for (int fm = 0; fm < 4; fm++)
#pragma unroll
        for (int fn = 0; fn < 4; fn++)
          acc[fm][fn] = __builtin_amdgcn_mfma_f32_16x16x32_bf16(af[fm][kk], bfr[fn][kk],
                                                                acc[fm][fn], 0, 0, 0);
  }
  __syncthreads();   // final tile's ds_reads drained before epilogue reuse

  // ---- epilogue, stage 1: acc -> LDS tile [128 t][128 h] bf16 (+bias) ----
  // D frag: col = lane&15, row = (lane>>4)*4 + i
#pragma unroll
  for (int fn = 0; fn < 4; fn++) {
    const int col = wc * 64 + fn * 16 + lr;
    const float bv = bias[n0 + col];
#pragma unroll
    for (int fm = 0; fm < 4; fm++) {
      const int row0 = wr * 64 + fm * 16 + (lane >> 4) * 4;
#pragma unroll
      for (int i = 0; i < 4; i++)
        tile[(row0 + i) * BN + col] = f2bf(acc[fm][fn][i] + bv);
    }
  }
  __syncthreads();

  // ---- epilogue, stage 2a: coalesced Yb store (256B rows) ----
  {
    const int erow = tid >> 4;            // 0..15
    const int ecol = (tid & 15) * 8;
#pragma unroll
    for (int p = 0; p < 8; p++) {
      const int row = p * 16 + erow;
      *(u16x8*)&Yb[(size_t)(m0 + row) * N_H + n0 + ecol] =
          *(const u16x8*)&tile[row * BN + ecol];
    }
  }
  // ---- epilogue, stage 2b: fused chunk-state (bit-identical math) ----
  {
    const int bidx = m0 >> 12;                 // batch
    const int c0   = (m0 & (T_SEQ - 1)) >> 5;  // first chunk in tile
    const int hl   = tid & 127;
    const int ck0  = tid >> 7;                 // 0..1; tasks ck0, ck0+2
    const int h    = n0 + hl;

    float a[4], bb[4], cc[4], dd[4];
#pragma unroll
    for (int l = 0; l < 4; l++) {
      a[l]  = 1.f / (1.f + __expf(-As[l * N_H + h]));
      bb[l] = Bs[l * N_H + h];
      cc[l] = Cs[l * N_H + h];
      dd[l] = Ds[l * N_H + h];
    }
#pragma unroll
    for (int p = 0; p < 2; p++) {
      const int ck = ck0 + p * 2;
      float s[4] = {0.f, 0.f, 0.f, 0.f};
#pragma unroll 4
      for (int t = 0; t < LC; t++) {
        float xv = bf2f(tile[(ck * LC + t) * BN + hl]);
#pragma unroll
        for (int l = 0; l < 4; l++) {
          s[l] = fmaf(a[l], s[l], bb[l] * xv);
          xv = fmaf(cc[l], s[l], dd[l]);
        }
      }
      f32x4 e;
      e[0] = s[0]; e[1] = s[1]; e[2] = s[2]; e[3] = s[3];
      ((f32x4*)E)[(size_t)(bidx * NC + c0 + ck) * N_H + h] = e;
    }
  }
}

// ============ chunked parallel scan (passes B and C) ============
// Pass B: per-(b,h) serial combine over chunks with P=M^LC -> start states S.
__global__ __launch_bounds__(256) void chunk_scan_kernel(
    const float* __restrict__ A, const float* __restrict__ B,
    const float* __restrict__ C, const float* __restrict__ E,
    float* __restrict__ S) {
  const int idx = blockIdx.x * 256 + threadIdx.x;
  const int b = idx >> 10;
  const int h = idx & (N_H - 1);

  float a[4], bcoef[4], ccoef[4];
#pragma unroll
  for (int l = 0; l < 4; l++) {
    a[l] = 1.f / (1.f + __expf(-A[l * N_H + h]));
    bcoef[l] = B[l * N_H + h];
    ccoef[l] = C[l * N_H + h];
  }

  float m[4][4] = {};
  m[0][0] = a[0];
  m[1][0] = bcoef[1] * ccoef[0] * a[0];
  m[1][1] = a[1];
  m[2][0] = bcoef[2] * ccoef[1] * m[1][0];
  m[2][1] = bcoef[2] * ccoef[1] * a[1];
  m[2][2] = a[2];
  m[3][0] = bcoef[3] * ccoef[2] * m[2][0];
  m[3][1] = bcoef[3] * ccoef[2] * m[2][1];
  m[3][2] = bcoef[3] * ccoef[2] * a[2];
  m[3][3] = a[3];

  // P = M^LC, LC=32 -> 5 squarings
#pragma unroll
  for (int it = 0; it < 5; it++) {
    float t[4][4];
#pragma unroll
    for (int i = 0; i < 4; i++)
#pragma unroll
      for (int j = 0; j < 4; j++) {
        float acc = 0.f;
#pragma unroll
        for (int k = 0; k < 4; k++) acc = fmaf(m[i][k], m[k][j], acc);
        t[i][j] = acc;
      }
#pragma unroll
    for (int i = 0; i < 4; i++)
#pragma unroll
      for (int j = 0; j < 4; j++) m[i][j] = t[i][j];
  }

  float s[4] = {0.f, 0.f, 0.f, 0.f};
  const f32x4* Ep = (const f32x4*)E + (size_t)b * NC * N_H + h;
  f32x4* Sp = (f32x4*)S + (size_t)b * NC * N_H + h;
#pragma unroll 4
  for (int c = 0; c < NC; c++) {
    f32x4 sv;
    sv[0] = s[0]; sv[1] = s[1]; sv[2] = s[2]; sv[3] = s[3];
    Sp[(size_t)c * N_H] = sv;
    f32x4 e = Ep[(size_t)c * N_H];
    float ns[4];
#pragma unroll
    for (int i = 0; i < 4; i++) {
      float acc = e[i];
#pragma unroll
      for (int k = 0; k < 4; k++) acc = fmaf(m[i][k], s[k], acc);
      ns[i] = acc;
    }
#pragma unroll
    for (int i = 0; i < 4; i++) s[i] = ns[i];
  }
}

// Pass C: recurrence from exact start state; reads bf16 Y, writes f32 out
__global__ __launch_bounds__(256) void chunk_apply_kernel(
    const ushort* __restrict__ Yb, float* __restrict__ out,
    const float* __restrict__ A, const float* __restrict__ B,
    const float* __restrict__ C, const float* __restrict__ D,
    const float* __restrict__ S) {
  const int b  = blockIdx.x / NC;
  const int c  = blockIdx.x % NC;
  const int h4 = threadIdx.x << 2;

  float a[4][4], bb[4][4], cc[4][4], dd[4][4];
#pragma unroll
  for (int l = 0; l < 4; l++) {
    f32x4 av = *(const f32x4*)(A + l * N_H + h4);
    f32x4 bv = *(const f32x4*)(B + l * N_H + h4);
    f32x4 cv = *(const f32x4*)(C + l * N_H + h4);
    f32x4 dv = *(const f32x4*)(D + l * N_H + h4);
#pragma unroll
    for (int ch = 0; ch < 4; ch++) {
      a[l][ch]  = 1.f / (1.f + __expf(-av[ch]));
      bb[l][ch] = bv[ch]; cc[l][ch] = cv[ch]; dd[l][ch] = dv[ch];
    }
  }

  float s[4][4];
  const f32x4* sp = (const f32x4*)S + (size_t)(b * NC + c) * N_H + h4;
#pragma unroll
  for (int ch = 0; ch < 4; ch++) {
    f32x4 sv = sp[ch];
    s[0][ch] = sv[0]; s[1][ch] = sv[1]; s[2][ch] = sv[2]; s[3][ch] = sv[3];
  }

  const ushort* ybase = Yb + ((size_t)b * T_SEQ + (size_t)c * LC) * N_H + h4;
  f32x4* op = (f32x4*)(out + ((size_t)b * T_SEQ + (size_t)c * LC) * N_H) + (h4 >> 2);
#pragma unroll 4
  for (int t = 0; t < LC; t++) {
    u16x4 xv = *(const u16x4*)(ybase + (size_t)t * N_H);
    f32x4 ov;
#pragma unroll
    for (int ch = 0; ch < 4; ch++) {
      float x = bf2f(xv[ch]);
#pragma unroll
      for (int l = 0; l < 4; l++) {
        s[l][ch] = fmaf(a[l][ch], s[l][ch], bb[l][ch] * x);
        x = fmaf(cc[l][ch], s[l][ch], dd[l][ch]);
      }
      ov[ch] = x;
    }
    op[(size_t)t * (N_H / 4)] = ov;
  }
}

extern "C" void kernel_launch(void* const* d_in, const int* in_sizes, int n_in,
                              void* d_out, int out_size, void* d_ws, size_t ws_size,
                              hipStream_t stream) {
  const float* x    = (const float*)d_in[0];
  const float* W    = (const float*)d_in[1];
  const float* b_in = (const float*)d_in[2];
  const float* A    = (const float*)d_in[3];
  const float* B    = (const float*)d_in[4];
  const float* C    = (const float*)d_in[5];
  const float* bias = (const float*)d_in[6];
  float* out = (float*)d_out;

  // ws layout (512 MiB available):
  //   Wt  [0,    1 MiB)  bf16 W^T
  //   Yb  [8,   72 MiB)  bf16 intermediate Y
  //   E   [112, 128 MiB) f32 chunk end states
  //   S   [128, 144 MiB) f32 chunk start states
  char* wsb = (char*)d_ws;
  ushort* Wt = (ushort*)wsb;
  ushort* Yb = (ushort*)(wsb + (size_t)8 * 1024 * 1024);
  float*  E  = (float*)(wsb + (size_t)112 * 1024 * 1024);
  float*  S  = E + (size_t)BT * NC * N_H * 4;

  prep_w_kernel<<<512, 256, 0, stream>>>(W, Wt);
  gemm_kernel<<<dim3(M_TOT / BM, N_H / BN), 256, 0, stream>>>(x, Wt, b_in, Yb,
                                                              A, B, C, bias, E);
  chunk_scan_kernel<<<(BT * N_H) / 256, 256, 0, stream>>>(A, B, C, E, S);
  chunk_apply_kernel<<<BT * NC, 256, 0, stream>>>(Yb, out, A, B, C, bias, S);
}

// Round 12
// 145.870 us; speedup vs baseline: 1.1905x; 1.1308x over previous
//
#include <hip/hip_runtime.h>
#include <hip/hip_bf16.h>
#include <stdint.h>

// Problem sizes (fixed by reference)
#define BT     8
#define T_SEQ  4096
#define K_F    512
#define N_H    1024
#define M_TOT  (BT * T_SEQ)   // 32768
#define NLAYER 4
#define LC     32             // chunk length for parallel scan
#define NC     (T_SEQ / LC)   // 128 chunks

typedef short  bf16x8 __attribute__((ext_vector_type(8)));
typedef float  f32x4  __attribute__((ext_vector_type(4)));
typedef ushort u16x8  __attribute__((ext_vector_type(8)));
typedef ushort u16x4  __attribute__((ext_vector_type(4)));

// f32 -> bf16 (round-to-nearest-even)
__device__ __forceinline__ ushort f2bf(float f) {
  uint32_t u = __builtin_bit_cast(uint32_t, f);
  u += 0x7fffu + ((u >> 16) & 1u);
  return (ushort)(u >> 16);
}
__device__ __forceinline__ float bf2f(ushort u) {
  uint32_t x = (uint32_t)u << 16;
  return __builtin_bit_cast(float, x);
}

// async global->LDS, 16B per lane (global_load_lds_dwordx4).
__device__ __forceinline__ void gload16(const void* g, void* l) {
  __builtin_amdgcn_global_load_lds(
      (const __attribute__((address_space(1))) uint32_t*)g,
      (__attribute__((address_space(3))) uint32_t*)l, 16, 0, 0);
}

// ---------------- prep: x f32->bf16 (8192 blocks) | W transpose (512 blocks) --
#define CVT_BLOCKS ((M_TOT * K_F) / (256 * 8))   // 8192

__global__ __launch_bounds__(256) void prep_kernel(const float* __restrict__ x,
                                                   ushort* __restrict__ xb,
                                                   const float* __restrict__ W,
                                                   ushort* __restrict__ Wt) {
  __shared__ float tile[32][33];
  const int bid = blockIdx.x;
  if (bid < CVT_BLOCKS) {
    const int i = bid * 256 + threadIdx.x;
    const float4* xv = (const float4*)x;
    float4 v0 = xv[2 * i + 0];
    float4 v1 = xv[2 * i + 1];
    u16x8 o;
    o[0] = f2bf(v0.x); o[1] = f2bf(v0.y); o[2] = f2bf(v0.z); o[3] = f2bf(v0.w);
    o[4] = f2bf(v1.x); o[5] = f2bf(v1.y); o[6] = f2bf(v1.z); o[7] = f2bf(v1.w);
    *((u16x8*)xb + i) = o;
  } else {
    const int idx = bid - CVT_BLOCKS;       // 0..511
    const int k0 = (idx & 15) * 32;         // 16 K-tiles
    const int n0 = (idx >> 4) * 32;         // 32 N-tiles
    const int lx = threadIdx.x & 31;
    const int ly = threadIdx.x >> 5;
#pragma unroll
    for (int j = 0; j < 32; j += 8)
      tile[ly + j][lx] = W[(size_t)(k0 + ly + j) * N_H + n0 + lx];
    __syncthreads();
#pragma unroll
    for (int j = 0; j < 32; j += 8)
      Wt[(size_t)(n0 + ly + j) * K_F + k0 + lx] = f2bf(tile[lx][ly + j]);
  }
}

// ---------------- GEMM + fused chunk-state (R7 trunk, unchanged) -----------
// Yb[M][N] = bf16(Xb[M][K] * Wt[N][K]^T + bias); m97 structure: 128x128 tile,
// BK=64, global_load_lds width=16, 2-barrier loop, 4 waves, ~4 blocks/CU.
// Epilogue: acc -> LDS bf16 tile (+bias) -> (a) coalesced u16x8 store to Yb,
// (b) fused SSM chunk-state (4 chunks x 128 h from LDS, bit-identical math).
#define BM 128
#define BN 128
#define BKK 64

__global__ __launch_bounds__(256) void gemm_kernel(
    const ushort* __restrict__ Xb, const ushort* __restrict__ Wt,
    const float* __restrict__ bias, ushort* __restrict__ Yb,
    const float* __restrict__ As, const float* __restrict__ Bs,
    const float* __restrict__ Cs, const float* __restrict__ Ds,
    float* __restrict__ E) {
  __shared__ ushort lds[BM * BKK * 2];   // lsA | lsB, 32 KiB; reused by epilogue
  ushort* lsA = lds;
  ushort* lsB = lds + BM * BKK;
  const int tid  = threadIdx.x;
  const int lane = tid & 63;
  const int wv   = tid >> 6;     // wave 0..3
  const int wr   = wv >> 1;      // wave row (0..1) -> 64 rows
  const int wc   = wv & 1;       // wave col (0..1) -> 64 cols
  const int m0   = blockIdx.x * BM;
  const int n0   = blockIdx.y * BN;

  const int srow = (lane >> 3);        // 0..7 within region
  const int scol = (lane & 7) * 8;     // k-elem offset
  const ushort* gA = Xb + (size_t)m0 * K_F + scol;
  const ushort* gB = Wt + (size_t)n0 * K_F + scol;

  f32x4 acc[4][4];
#pragma unroll
  for (int i = 0; i < 4; i++)
#pragma unroll
    for (int j = 0; j < 4; j++) acc[i][j] = (f32x4)0.0f;

  const int lr = lane & 15;
  const int kg = (lane >> 4) * 8;

  for (int kt = 0; kt < K_F; kt += BKK) {
#pragma unroll
    for (int i = 0; i < 4; i++) {
      const int reg = wv * 4 + i;          // region id 0..15
      const int r   = reg * 8 + srow;      // tile row
      gload16(gA + (size_t)r * K_F + kt, &lsA[reg * 512]);
      gload16(gB + (size_t)r * K_F + kt, &lsB[reg * 512]);
    }
    __syncthreads();

    bf16x8 af[4][2], bfr[4][2];
#pragma unroll
    for (int fm = 0; fm < 4; fm++)
#pragma unroll
      for (int kk = 0; kk < 2; kk++)
        af[fm][kk] = *(const bf16x8*)&lsA[(wr * 64 + fm * 16 + lr) * BKK + kk * 32 + kg];
#pragma unroll
    for (int fn = 0; fn < 4; fn++)
#pragma unroll
      for (int kk = 0; kk < 2; kk++)
        bfr[fn][kk] = *(const bf16x8*)&lsB[(wc * 64 + fn * 16 + lr) * BKK + kk * 32 + kg];

#pragma unroll
    for (int kk = 0; kk < 2; kk++)
#pragma unroll
      for (int fm = 0; fm < 4; fm++)
#pragma unroll
        for (int fn = 0; fn < 4; fn++)
          acc[fm][fn] = __builtin_amdgcn_mfma_f32_16x16x32_bf16(af[fm][kk], bfr[fn][kk],
                                                                acc[fm][fn], 0, 0, 0);
    __syncthreads();
  }

  // ---- epilogue, stage 1: acc -> LDS tile [128 t][128 h] bf16 (+bias) ----
#pragma unroll
  for (int fn = 0; fn < 4; fn++) {
    const int col = wc * 64 + fn * 16 + lr;
    const float bv = bias[n0 + col];
#pragma unroll
    for (int fm = 0; fm < 4; fm++) {
      const int row0 = wr * 64 + fm * 16 + (lane >> 4) * 4;
#pragma unroll
      for (int i = 0; i < 4; i++)
        lds[(row0 + i) * BN + col] = f2bf(acc[fm][fn][i] + bv);
    }
  }
  __syncthreads();

  // ---- epilogue, stage 2a: coalesced Yb store (256B rows) ----
  const int erow = tid >> 4;            // 0..15
  const int ecol = (tid & 15) * 8;      // elem offset, 16B per lane
#pragma unroll
  for (int p = 0; p < 8; p++) {
    const int row = p * 16 + erow;
    u16x8 v = *(const u16x8*)&lds[row * BN + ecol];
    *(u16x8*)&Yb[(size_t)(m0 + row) * N_H + n0 + ecol] = v;
  }

  // ---- epilogue, stage 2b: fused chunk-state over the LDS tile ----
  {
    const int bidx = m0 >> 12;           // m0 / T_SEQ
    const int c0   = (m0 & (T_SEQ - 1)) >> 5;  // first chunk in tile
    const int hl   = tid & 127;          // local h (same for both tasks)
    const int ck0  = tid >> 7;           // 0..1; tasks: ck0 and ck0+2
    const int h    = n0 + hl;

    float a[4], bb[4], cc[4], dd[4];
#pragma unroll
    for (int l = 0; l < 4; l++) {
      a[l]  = 1.f / (1.f + __expf(-As[l * N_H + h]));
      bb[l] = Bs[l * N_H + h];
      cc[l] = Cs[l * N_H + h];
      dd[l] = Ds[l * N_H + h];
    }

#pragma unroll
    for (int p = 0; p < 2; p++) {
      const int ck = ck0 + p * 2;
      float s[4] = {0.f, 0.f, 0.f, 0.f};
#pragma unroll 4
      for (int t = 0; t < LC; t++) {
        float xv = bf2f(lds[(ck * LC + t) * BN + hl]);
#pragma unroll
        for (int l = 0; l < 4; l++) {
          s[l] = fmaf(a[l], s[l], bb[l] * xv);
          xv = fmaf(cc[l], s[l], dd[l]);
        }
      }
      f32x4 e;
      e[0] = s[0]; e[1] = s[1]; e[2] = s[2]; e[3] = s[3];
      ((f32x4*)E)[(size_t)(bidx * NC + c0 + ck) * N_H + h] = e;
    }
  }
}

// ============ chunked parallel scan (passes B and C) ============
// Pass B: per-(b,h) serial combine over chunks with P=M^LC -> start states S.
__global__ __launch_bounds__(256) void chunk_scan_kernel(
    const float* __restrict__ A, const float* __restrict__ B,
    const float* __restrict__ C, const float* __restrict__ E,
    float* __restrict__ S) {
  const int idx = blockIdx.x * 256 + threadIdx.x;
  const int b = idx >> 10;
  const int h = idx & (N_H - 1);

  float a[4], bcoef[4], ccoef[4];
#pragma unroll
  for (int l = 0; l < 4; l++) {
    a[l] = 1.f / (1.f + __expf(-A[l * N_H + h]));
    bcoef[l] = B[l * N_H + h];
    ccoef[l] = C[l * N_H + h];
  }

  float m[4][4] = {};
  m[0][0] = a[0];
  m[1][0] = bcoef[1] * ccoef[0] * a[0];
  m[1][1] = a[1];
  m[2][0] = bcoef[2] * ccoef[1] * m[1][0];
  m[2][1] = bcoef[2] * ccoef[1] * a[1];
  m[2][2] = a[2];
  m[3][0] = bcoef[3] * ccoef[2] * m[2][0];
  m[3][1] = bcoef[3] * ccoef[2] * m[2][1];
  m[3][2] = bcoef[3] * ccoef[2] * a[2];
  m[3][3] = a[3];

  // P = M^LC, LC=32 -> 5 squarings
#pragma unroll
  for (int it = 0; it < 5; it++) {
    float t[4][4];
#pragma unroll
    for (int i = 0; i < 4; i++)
#pragma unroll
      for (int j = 0; j < 4; j++) {
        float acc = 0.f;
#pragma unroll
        for (int k = 0; k < 4; k++) acc = fmaf(m[i][k], m[k][j], acc);
        t[i][j] = acc;
      }
#pragma unroll
    for (int i = 0; i < 4; i++)
#pragma unroll
      for (int j = 0; j < 4; j++) m[i][j] = t[i][j];
  }

  float s[4] = {0.f, 0.f, 0.f, 0.f};
  const f32x4* Ep = (const f32x4*)E + (size_t)b * NC * N_H + h;
  f32x4* Sp = (f32x4*)S + (size_t)b * NC * N_H + h;
#pragma unroll 4
  for (int c = 0; c < NC; c++) {
    f32x4 sv;
    sv[0] = s[0]; sv[1] = s[1]; sv[2] = s[2]; sv[3] = s[3];
    Sp[(size_t)c * N_H] = sv;
    f32x4 e = Ep[(size_t)c * N_H];
    float ns[4];
#pragma unroll
    for (int i = 0; i < 4; i++) {
      float acc = e[i];
#pragma unroll
      for (int k = 0; k < 4; k++) acc = fmaf(m[i][k], s[k], acc);
      ns[i] = acc;
    }
#pragma unroll
    for (int i = 0; i < 4; i++) s[i] = ns[i];
  }
}

// Pass C: recurrence from exact start state; reads bf16 Y, writes f32 out.
// `out` is a 134 MB write-once stream -> nontemporal stores (avoid L2/L3
// write-allocate pollution, which also evicts the Yb being streamed in).
__global__ __launch_bounds__(256) void chunk_apply_kernel(
    const ushort* __restrict__ Yb, float* __restrict__ out,
    const float* __restrict__ A, const float* __restrict__ B,
    const float* __restrict__ C, const float* __restrict__ D,
    const float* __restrict__ S) {
  const int b  = blockIdx.x / NC;
  const int c  = blockIdx.x % NC;
  const int h4 = threadIdx.x << 2;

  float a[4][4], bb[4][4], cc[4][4], dd[4][4];
#pragma unroll
  for (int l = 0; l < 4; l++) {
    f32x4 av = *(const f32x4*)(A + l * N_H + h4);
    f32x4 bv = *(const f32x4*)(B + l * N_H + h4);
    f32x4 cv = *(const f32x4*)(C + l * N_H + h4);
    f32x4 dv = *(const f32x4*)(D + l * N_H + h4);
#pragma unroll
    for (int ch = 0; ch < 4; ch++) {
      a[l][ch]  = 1.f / (1.f + __expf(-av[ch]));
      bb[l][ch] = bv[ch]; cc[l][ch] = cv[ch]; dd[l][ch] = dv[ch];
    }
  }

  float s[4][4];
  const f32x4* sp = (const f32x4*)S + (size_t)(b * NC + c) * N_H + h4;
#pragma unroll
  for (int ch = 0; ch < 4; ch++) {
    f32x4 sv = sp[ch];
    s[0][ch] = sv[0]; s[1][ch] = sv[1]; s[2][ch] = sv[2]; s[3][ch] = sv[3];
  }

  const ushort* ybase = Yb + ((size_t)b * T_SEQ + (size_t)c * LC) * N_H + h4;
  f32x4* op = (f32x4*)(out + ((size_t)b * T_SEQ + (size_t)c * LC) * N_H) + (h4 >> 2);
#pragma unroll 4
  for (int t = 0; t < LC; t++) {
    u16x4 xv = *(const u16x4*)(ybase + (size_t)t * N_H);
    f32x4 ov;
#pragma unroll
    for (int ch = 0; ch < 4; ch++) {
      float x = bf2f(xv[ch]);
#pragma unroll
      for (int l = 0; l < 4; l++) {
        s[l][ch] = fmaf(a[l][ch], s[l][ch], bb[l][ch] * x);
        x = fmaf(cc[l][ch], s[l][ch], dd[l][ch]);
      }
      ov[ch] = x;
    }
    __builtin_nontemporal_store(ov, op + (size_t)t * (N_H / 4));
  }
}

extern "C" void kernel_launch(void* const* d_in, const int* in_sizes, int n_in,
                              void* d_out, int out_size, void* d_ws, size_t ws_size,
                              hipStream_t stream) {
  const float* x    = (const float*)d_in[0];
  const float* W    = (const float*)d_in[1];
  const float* b_in = (const float*)d_in[2];
  const float* A    = (const float*)d_in[3];
  const float* B    = (const float*)d_in[4];
  const float* C    = (const float*)d_in[5];
  const float* bias = (const float*)d_in[6];
  float* out = (float*)d_out;

  // ws layout (512 MiB available):
  //   xb  [0,   32 MiB)  bf16 x
  //   Wt  [32,  33 MiB)  bf16 W^T
  //   Yb  [40, 104 MiB)  bf16 intermediate Y
  //   E   [112,128 MiB)  f32 chunk end states
  //   S   [128,144 MiB)  f32 chunk start states
  char* wsb = (char*)d_ws;
  ushort* xb = (ushort*)wsb;
  ushort* Wt = (ushort*)(wsb + (size_t)33 * 1024 * 1024 - (size_t)N_H * K_F * 2);
  ushort* Yb = (ushort*)(wsb + (size_t)40 * 1024 * 1024);
  float*  E  = (float*)(wsb + (size_t)112 * 1024 * 1024);
  float*  S  = E + (size_t)BT * NC * N_H * 4;

  prep_kernel<<<CVT_BLOCKS + 512, 256, 0, stream>>>(x, xb, W, Wt);
  gemm_kernel<<<dim3(M_TOT / BM, N_H / BN), 256, 0, stream>>>(xb, Wt, b_in, Yb,
                                                              A, B, C, bias, E);
  chunk_scan_kernel<<<(BT * N_H) / 256, 256, 0, stream>>>(A, B, C, E, S);
  chunk_apply_kernel<<<BT * NC, 256, 0, stream>>>(Yb, out, A, B, C, bias, S);
}